// Round 1
// baseline (74.545 us; speedup 1.0000x reference)
//
#include <hip/hip_runtime.h>

#define B_ 32
#define Q_ 16
#define D_ 2048
#define E_ 300
#define NB 30
#define SPLIT 8
#define ROWS (D_ / SPLIT)

// ---------------- Kernel 1: query prep (qn, gate logits) + hist zero ----------------
__global__ __launch_bounds__(256) void drmm_prep(
    const int* __restrict__ query, const float* __restrict__ emb,
    const float* __restrict__ Wg, const float* __restrict__ bg,
    float* __restrict__ qn, float* __restrict__ gbuf, int* __restrict__ hist)
{
    const int b = blockIdx.x, tid = threadIdx.x;
    const int wid = tid >> 6, lane = tid & 63;

    // zero global histogram (32*16*30 ints) across the 32 blocks
    for (int i = b * 256 + tid; i < B_ * Q_ * NB; i += B_ * 256) hist[i] = 0;

    for (int qq = wid; qq < Q_; qq += 4) {
        const int id = query[b * Q_ + qq];
        const float m = (id > 0) ? 1.f : 0.f;
        const float* row = emb + (long long)((id > 0) ? id : 0) * E_;
        float v[5];
        float ss = 0.f, dg = 0.f;
        #pragma unroll
        for (int k = 0; k < 5; ++k) {
            const int e = lane + 64 * k;
            float x = 0.f, w = 0.f;
            if (e < E_) { x = row[e] * m; w = Wg[e]; }
            v[k] = x;
            ss = fmaf(x, x, ss);
            dg = fmaf(x, w, dg);
        }
        #pragma unroll
        for (int off = 32; off > 0; off >>= 1) {
            ss += __shfl_xor(ss, off);
            dg += __shfl_xor(dg, off);
        }
        // masked row: ss==0 -> rn=inf -> qn = 0*inf = NaN, matching reference 0/0
        const float rn = 1.0f / sqrtf(ss);
        #pragma unroll
        for (int k = 0; k < 5; ++k) {
            const int e = lane + 64 * k;
            if (e < E_) qn[((size_t)(b * Q_ + qq)) * E_ + e] = v[k] * rn;
        }
        if (lane == 0) gbuf[b * Q_ + qq] = tanhf(dg + bg[0]);
    }
}

// ---------------- Kernel 2: interaction dots + histogram ----------------
__global__ __launch_bounds__(256) void drmm_main(
    const int* __restrict__ doc, const float* __restrict__ emb,
    const float* __restrict__ qn, int* __restrict__ hist)
{
    __shared__ __align__(16) float qs[Q_ * E_];      // 19.2 KB
    __shared__ int whist[4][Q_ * NB];                // per-wave histograms, 7.68 KB

    const int tid = threadIdx.x;
    const int b = blockIdx.x / SPLIT, sp = blockIdx.x % SPLIT;
    const int lane = tid & 63, wid = tid >> 6;

    // stage qn tile for this batch
    const float4* qb = (const float4*)(qn + (size_t)b * Q_ * E_);
    for (int i = tid; i < Q_ * E_ / 4; i += 256) ((float4*)qs)[i] = qb[i];
    for (int i = tid; i < 4 * Q_ * NB; i += 256) ((int*)whist)[i] = 0;
    __syncthreads();

    const int d = sp * ROWS + tid;           // ROWS==256 == blockDim
    const int id = doc[b * D_ + d];
    const bool rowok = (id > 0);
    const float4* row = (const float4*)(emb + (long long)(rowok ? id : 0) * E_);

    float acc[Q_];
    #pragma unroll
    for (int q = 0; q < Q_; ++q) acc[q] = 0.f;
    float ss = 0.f;

    #pragma unroll 5
    for (int c = 0; c < E_ / 4; ++c) {
        const float4 v = row[c];
        ss = fmaf(v.x, v.x, fmaf(v.y, v.y, fmaf(v.z, v.z, fmaf(v.w, v.w, ss))));
        #pragma unroll
        for (int q = 0; q < Q_; ++q) {
            const float4 u = *(const float4*)(qs + q * E_ + c * 4);
            acc[q] = fmaf(v.x, u.x, fmaf(v.y, u.y, fmaf(v.z, u.z, fmaf(v.w, u.w, acc[q]))));
        }
    }

    const float rn = 1.0f / sqrtf(ss);   // ss==0 -> inf -> sim inf/NaN -> dropped

    #pragma unroll
    for (int q = 0; q < Q_; ++q) {
        const float x = acc[q] * rn;     // NaN qn rows (masked q) -> NaN -> dropped
        const float t = (x + 1.0f) * 15.0f;
        int bin = (int)floorf(t);
        bin = bin < 0 ? 0 : (bin > NB - 1 ? NB - 1 : bin);
        const bool valid = rowok && (x >= -1.0f) && (x <= 1.0f);
        const unsigned long long vm = __ballot(valid);
        int myc = 0;
        #pragma unroll
        for (int L = 0; L < NB; ++L) {
            const unsigned long long mL = __ballot(bin == L) & vm;
            const int c = (int)__popcll(mL);
            myc = (lane == L) ? c : myc;
        }
        if (lane < NB) whist[wid][q * NB + lane] += myc;
    }
    __syncthreads();

    // reduce 4 wave copies -> global atomics
    for (int i = tid; i < Q_ * NB; i += 256) {
        const int s = whist[0][i] + whist[1][i] + whist[2][i] + whist[3][i];
        if (s) atomicAdd(&hist[b * Q_ * NB + i], s);
    }
}

// ---------------- Kernel 3: log1p + FFN + gated sum ----------------
__global__ __launch_bounds__(64) void drmm_final(
    const int* __restrict__ hist, const float* __restrict__ gbuf,
    const int* __restrict__ query,
    const float* __restrict__ W1, const float* __restrict__ b1,
    const float* __restrict__ W2, const float* __restrict__ b2,
    const float* __restrict__ W3, const float* __restrict__ b3,
    float* __restrict__ out)
{
    const int b = blockIdx.x, lane = threadIdx.x;
    float z = 0.f, e = 0.f;
    if (lane < Q_) {
        const int* h = hist + (b * Q_ + lane) * NB;
        float pre1[5];
        #pragma unroll
        for (int u = 0; u < 5; ++u) pre1[u] = b1[u];
        #pragma unroll
        for (int k = 0; k < NB; ++k) {
            const float hv = log1pf((float)h[k]);
            #pragma unroll
            for (int u = 0; u < 5; ++u) pre1[u] = fmaf(hv, W1[k * 5 + u], pre1[u]);
        }
        float z2 = b2[0];
        #pragma unroll
        for (int u = 0; u < 5; ++u) z2 = fmaf(tanhf(pre1[u]), W2[u], z2);
        const float z3 = fmaf(tanhf(z2), W3[0], b3[0]);
        z = tanhf(z3);
        const int id = query[b * Q_ + lane];
        const float g = gbuf[b * Q_ + lane];
        e = (id > 0) ? expf(g) : 0.f;
    }
    float ze = z * e, se = e;
    #pragma unroll
    for (int off = 32; off > 0; off >>= 1) {
        ze += __shfl_xor(ze, off);
        se += __shfl_xor(se, off);
    }
    if (lane == 0) out[b] = ze / (se + 1e-5f);
}

// ---------------- launch ----------------
extern "C" void kernel_launch(void* const* d_in, const int* in_sizes, int n_in,
                              void* d_out, int out_size, void* d_ws, size_t ws_size,
                              hipStream_t stream)
{
    const int*   query = (const int*)d_in[0];
    const int*   doc   = (const int*)d_in[1];
    // d_in[2] = q_idf (unused by reference)
    const float* emb   = (const float*)d_in[3];
    const float* W1    = (const float*)d_in[4];
    const float* b1    = (const float*)d_in[5];
    const float* W2    = (const float*)d_in[6];
    const float* b2    = (const float*)d_in[7];
    const float* W3    = (const float*)d_in[8];
    const float* b3    = (const float*)d_in[9];
    const float* Wg    = (const float*)d_in[10];
    const float* bg    = (const float*)d_in[11];
    float* out = (float*)d_out;

    // workspace layout
    char* ws = (char*)d_ws;
    float* qn   = (float*)ws;                        // 512*300 f32 = 614400 B
    float* gbuf = (float*)(ws + 614400);             // 512 f32    = 2048 B
    int*   hist = (int*)(ws + 614400 + 2048);        // 15360 ints = 61440 B

    drmm_prep<<<B_, 256, 0, stream>>>(query, emb, Wg, bg, qn, gbuf, hist);
    drmm_main<<<B_ * SPLIT, 256, 0, stream>>>(doc, emb, qn, hist);
    drmm_final<<<B_, 64, 0, stream>>>(hist, gbuf, query,
                                      W1, b1, W2, b2, W3, b3, out);
}

// Round 2
// 58.497 us; speedup vs baseline: 1.2743x; 1.2743x over previous
//
#include <hip/hip_runtime.h>

#define B_ 32
#define Q_ 16
#define D_ 2048
#define E_ 300
#define EF4 75              // float4s per embedding row
#define NB 30
#define TILE 64             // doc rows per block
#define TPB (D_ / TILE)     // tiles per batch = 32

// ---------------- Kernel 1: query prep (qn, gate logits) + hist zero ----------------
__global__ __launch_bounds__(256) void drmm_prep(
    const int* __restrict__ query, const float* __restrict__ emb,
    const float* __restrict__ Wg, const float* __restrict__ bg,
    float* __restrict__ qn, float* __restrict__ gbuf, int* __restrict__ hist)
{
    const int b = blockIdx.x, tid = threadIdx.x;
    const int wid = tid >> 6, lane = tid & 63;

    // zero global histogram (32*16*30 ints) across the 32 blocks
    for (int i = b * 256 + tid; i < B_ * Q_ * NB; i += B_ * 256) hist[i] = 0;

    for (int qq = wid; qq < Q_; qq += 4) {
        const int id = query[b * Q_ + qq];
        const float m = (id > 0) ? 1.f : 0.f;
        const float* row = emb + (long long)((id > 0) ? id : 0) * E_;
        float v[5];
        float ss = 0.f, dg = 0.f;
        #pragma unroll
        for (int k = 0; k < 5; ++k) {
            const int e = lane + 64 * k;
            float x = 0.f, w = 0.f;
            if (e < E_) { x = row[e] * m; w = Wg[e]; }
            v[k] = x;
            ss = fmaf(x, x, ss);
            dg = fmaf(x, w, dg);
        }
        #pragma unroll
        for (int off = 32; off > 0; off >>= 1) {
            ss += __shfl_xor(ss, off);
            dg += __shfl_xor(dg, off);
        }
        // masked row: ss==0 -> rn=inf -> qn = 0*inf = NaN, matching reference 0/0
        const float rn = 1.0f / sqrtf(ss);
        #pragma unroll
        for (int k = 0; k < 5; ++k) {
            const int e = lane + 64 * k;
            if (e < E_) qn[((size_t)(b * Q_ + qq)) * E_ + e] = v[k] * rn;
        }
        if (lane == 0) gbuf[b * Q_ + qq] = tanhf(dg + bg[0]);
    }
}

// ---------------- Kernel 2: interaction dots + histogram ----------------
// Block = 64 doc rows (lane = row). The 4 waves split E into float4 chunks
// {19,19,19,18}; partial dots combined through LDS; binning via LDS atomics
// with q split across waves (no two waves touch the same q's bins).
__global__ __launch_bounds__(256, 4) void drmm_main(
    const int* __restrict__ doc, const float* __restrict__ emb,
    const float* __restrict__ qn, int* __restrict__ hist)
{
    __shared__ __align__(16) float qs[Q_ * E_];      // 19200 B
    __shared__ float part[4][Q_ + 1][TILE];          // 4*17*64*4 = 17408 B
    __shared__ int   whist[Q_ * NB];                 // 1920 B

    const int tid = threadIdx.x;
    const int b = blockIdx.x / TPB, tile = blockIdx.x % TPB;
    const int lane = tid & 63, w = tid >> 6;

    // stage qn tile for this batch + zero block histogram
    const float4* qb = (const float4*)(qn + (size_t)b * Q_ * E_);
    float4* qs4w = (float4*)qs;
    for (int i = tid; i < Q_ * EF4; i += 256) qs4w[i] = qb[i];
    for (int i = tid; i < Q_ * NB; i += 256) whist[i] = 0;
    __syncthreads();

    const int d = tile * TILE + lane;
    const int id = doc[b * D_ + d];
    const bool rowok = (id > 0);
    const float4* row = (const float4*)(emb + (long long)(rowok ? id : 0) * E_);
    const float4* qs4 = (const float4*)qs;

    const int cbeg = w * 19;                 // chunks: 19,19,19,18 float4s
    const int cnt  = (w == 3) ? 18 : 19;

    float acc[Q_];
    #pragma unroll
    for (int q = 0; q < Q_; ++q) acc[q] = 0.f;
    float ss = 0.f;

    #pragma unroll 4
    for (int k = 0; k < cnt; ++k) {
        const int c = cbeg + k;
        const float4 v = row[c];             // per-lane row, scattered
        ss = fmaf(v.x, v.x, fmaf(v.y, v.y, fmaf(v.z, v.z, fmaf(v.w, v.w, ss))));
        #pragma unroll
        for (int q = 0; q < Q_; ++q) {
            const float4 u = qs4[q * EF4 + c];   // wave-uniform broadcast read
            acc[q] = fmaf(v.x, u.x, fmaf(v.y, u.y, fmaf(v.z, u.z, fmaf(v.w, u.w, acc[q]))));
        }
    }

    // write partial dots + partial sumsq
    #pragma unroll
    for (int q = 0; q < Q_; ++q) part[w][q][lane] = acc[q];
    part[w][Q_][lane] = ss;
    __syncthreads();

    // combine across waves; wave w bins q in [4w, 4w+4)
    const float sst = part[0][Q_][lane] + part[1][Q_][lane]
                    + part[2][Q_][lane] + part[3][Q_][lane];
    const float rn = 1.0f / sqrtf(sst);      // zeros -> inf -> NaN sims -> dropped
    #pragma unroll
    for (int qq = 0; qq < 4; ++qq) {
        const int q = w * 4 + qq;
        const float s = part[0][q][lane] + part[1][q][lane]
                      + part[2][q][lane] + part[3][q][lane];
        const float x = s * rn;              // NaN (masked q row) -> dropped
        const float t = (x + 1.0f) * (NB * 0.5f);
        int bin = (int)floorf(t);
        bin = bin < 0 ? 0 : (bin > NB - 1 ? NB - 1 : bin);
        if (rowok && x >= -1.0f && x <= 1.0f)
            atomicAdd(&whist[q * NB + bin], 1);
    }
    __syncthreads();

    // flush block histogram to global
    for (int i = tid; i < Q_ * NB; i += 256) {
        const int v = whist[i];
        if (v) atomicAdd(&hist[b * Q_ * NB + i], v);
    }
}

// ---------------- Kernel 3: log1p + FFN + gated sum ----------------
__global__ __launch_bounds__(64) void drmm_final(
    const int* __restrict__ hist, const float* __restrict__ gbuf,
    const int* __restrict__ query,
    const float* __restrict__ W1, const float* __restrict__ b1,
    const float* __restrict__ W2, const float* __restrict__ b2,
    const float* __restrict__ W3, const float* __restrict__ b3,
    float* __restrict__ out)
{
    const int b = blockIdx.x, lane = threadIdx.x;
    float z = 0.f, e = 0.f;
    if (lane < Q_) {
        const int* h = hist + (b * Q_ + lane) * NB;
        float pre1[5];
        #pragma unroll
        for (int u = 0; u < 5; ++u) pre1[u] = b1[u];
        #pragma unroll
        for (int k = 0; k < NB; ++k) {
            const float hv = log1pf((float)h[k]);
            #pragma unroll
            for (int u = 0; u < 5; ++u) pre1[u] = fmaf(hv, W1[k * 5 + u], pre1[u]);
        }
        float z2 = b2[0];
        #pragma unroll
        for (int u = 0; u < 5; ++u) z2 = fmaf(tanhf(pre1[u]), W2[u], z2);
        const float z3 = fmaf(tanhf(z2), W3[0], b3[0]);
        z = tanhf(z3);
        const int id = query[b * Q_ + lane];
        const float g = gbuf[b * Q_ + lane];
        e = (id > 0) ? expf(g) : 0.f;
    }
    float ze = z * e, se = e;
    #pragma unroll
    for (int off = 32; off > 0; off >>= 1) {
        ze += __shfl_xor(ze, off);
        se += __shfl_xor(se, off);
    }
    if (lane == 0) out[b] = ze / (se + 1e-5f);
}

// ---------------- launch ----------------
extern "C" void kernel_launch(void* const* d_in, const int* in_sizes, int n_in,
                              void* d_out, int out_size, void* d_ws, size_t ws_size,
                              hipStream_t stream)
{
    const int*   query = (const int*)d_in[0];
    const int*   doc   = (const int*)d_in[1];
    // d_in[2] = q_idf (unused by reference)
    const float* emb   = (const float*)d_in[3];
    const float* W1    = (const float*)d_in[4];
    const float* b1    = (const float*)d_in[5];
    const float* W2    = (const float*)d_in[6];
    const float* b2    = (const float*)d_in[7];
    const float* W3    = (const float*)d_in[8];
    const float* b3    = (const float*)d_in[9];
    const float* Wg    = (const float*)d_in[10];
    const float* bg    = (const float*)d_in[11];
    float* out = (float*)d_out;

    // workspace layout
    char* ws = (char*)d_ws;
    float* qn   = (float*)ws;                        // 512*300 f32 = 614400 B
    float* gbuf = (float*)(ws + 614400);             // 512 f32    = 2048 B
    int*   hist = (int*)(ws + 614400 + 2048);        // 15360 ints = 61440 B

    drmm_prep<<<B_, 256, 0, stream>>>(query, emb, Wg, bg, qn, gbuf, hist);
    drmm_main<<<B_ * TPB, 256, 0, stream>>>(doc, emb, qn, hist);
    drmm_final<<<B_, 64, 0, stream>>>(hist, gbuf, query,
                                      W1, b1, W2, b2, W3, b3, out);
}

// Round 3
// 50.819 us; speedup vs baseline: 1.4669x; 1.1511x over previous
//
#include <hip/hip_runtime.h>

#define B_ 32
#define Q_ 16
#define D_ 2048
#define E_ 300
#define EF4 75              // float4s per embedding row
#define NB 30
#define TILE 64             // doc rows per block
#define TPB (D_ / TILE)     // tiles per batch = 32

// Hardware-TRANS-pipe transcendentals: single v_exp_f32 / v_log_f32 instead of
// branchy ocml slow paths (R2 post-mortem: drmm_final 99% stalled on these).
__device__ __forceinline__ float fast_tanh(float x) {
    const float t = __expf(-2.0f * fabsf(x));      // (0,1], never overflows
    const float r = (1.0f - t) / (1.0f + t);
    return copysignf(r, x);
}
__device__ __forceinline__ float fast_log1p(float x) {   // x >= 0 here
    return __logf(1.0f + x);
}

// ---------------- Kernel 1: query prep (qn, gate logits) + hist zero ----------------
__global__ __launch_bounds__(256) void drmm_prep(
    const int* __restrict__ query, const float* __restrict__ emb,
    const float* __restrict__ Wg, const float* __restrict__ bg,
    float* __restrict__ qn, float* __restrict__ gbuf, int* __restrict__ hist)
{
    const int b = blockIdx.x, tid = threadIdx.x;
    const int wid = tid >> 6, lane = tid & 63;

    // zero global histogram (32*16*30 ints) across the 32 blocks
    for (int i = b * 256 + tid; i < B_ * Q_ * NB; i += B_ * 256) hist[i] = 0;

    for (int qq = wid; qq < Q_; qq += 4) {
        const int id = query[b * Q_ + qq];
        const float m = (id > 0) ? 1.f : 0.f;
        const float* row = emb + (long long)((id > 0) ? id : 0) * E_;
        float v[5];
        float ss = 0.f, dg = 0.f;
        #pragma unroll
        for (int k = 0; k < 5; ++k) {
            const int e = lane + 64 * k;
            float x = 0.f, w = 0.f;
            if (e < E_) { x = row[e] * m; w = Wg[e]; }
            v[k] = x;
            ss = fmaf(x, x, ss);
            dg = fmaf(x, w, dg);
        }
        #pragma unroll
        for (int off = 32; off > 0; off >>= 1) {
            ss += __shfl_xor(ss, off);
            dg += __shfl_xor(dg, off);
        }
        // masked row: ss==0 -> rn=inf -> qn = 0*inf = NaN, matching reference 0/0
        const float rn = 1.0f / sqrtf(ss);
        #pragma unroll
        for (int k = 0; k < 5; ++k) {
            const int e = lane + 64 * k;
            if (e < E_) qn[((size_t)(b * Q_ + qq)) * E_ + e] = v[k] * rn;
        }
        if (lane == 0) gbuf[b * Q_ + qq] = fast_tanh(dg + bg[0]);
    }
}

// ---------------- Kernel 2: interaction dots + histogram ----------------
// Block = 64 doc rows (lane = row). The 4 waves split E into float4 chunks
// {19,19,19,18}; partial dots combined through LDS; binning via LDS atomics
// with q split across waves (no two waves touch the same q's bins).
__global__ __launch_bounds__(256, 4) void drmm_main(
    const int* __restrict__ doc, const float* __restrict__ emb,
    const float* __restrict__ qn, int* __restrict__ hist)
{
    __shared__ __align__(16) float qs[Q_ * E_];      // 19200 B
    __shared__ float part[4][Q_ + 1][TILE];          // 4*17*64*4 = 17408 B
    __shared__ int   whist[Q_ * NB];                 // 1920 B

    const int tid = threadIdx.x;
    const int b = blockIdx.x / TPB, tile = blockIdx.x % TPB;
    const int lane = tid & 63, w = tid >> 6;

    // stage qn tile for this batch + zero block histogram
    const float4* qb = (const float4*)(qn + (size_t)b * Q_ * E_);
    float4* qs4w = (float4*)qs;
    for (int i = tid; i < Q_ * EF4; i += 256) qs4w[i] = qb[i];
    for (int i = tid; i < Q_ * NB; i += 256) whist[i] = 0;
    __syncthreads();

    const int d = tile * TILE + lane;
    const int id = doc[b * D_ + d];
    const bool rowok = (id > 0);
    const float4* row = (const float4*)(emb + (long long)(rowok ? id : 0) * E_);
    const float4* qs4 = (const float4*)qs;

    const int cbeg = w * 19;                 // chunks: 19,19,19,18 float4s
    const int cnt  = (w == 3) ? 18 : 19;

    float acc[Q_];
    #pragma unroll
    for (int q = 0; q < Q_; ++q) acc[q] = 0.f;
    float ss = 0.f;

    #pragma unroll 4
    for (int k = 0; k < cnt; ++k) {
        const int c = cbeg + k;
        const float4 v = row[c];             // per-lane row, scattered
        ss = fmaf(v.x, v.x, fmaf(v.y, v.y, fmaf(v.z, v.z, fmaf(v.w, v.w, ss))));
        #pragma unroll
        for (int q = 0; q < Q_; ++q) {
            const float4 u = qs4[q * EF4 + c];   // wave-uniform broadcast read
            acc[q] = fmaf(v.x, u.x, fmaf(v.y, u.y, fmaf(v.z, u.z, fmaf(v.w, u.w, acc[q]))));
        }
    }

    // write partial dots + partial sumsq
    #pragma unroll
    for (int q = 0; q < Q_; ++q) part[w][q][lane] = acc[q];
    part[w][Q_][lane] = ss;
    __syncthreads();

    // combine across waves; wave w bins q in [4w, 4w+4)
    const float sst = part[0][Q_][lane] + part[1][Q_][lane]
                    + part[2][Q_][lane] + part[3][Q_][lane];
    const float rn = 1.0f / sqrtf(sst);      // zeros -> inf -> NaN sims -> dropped
    #pragma unroll
    for (int qq = 0; qq < 4; ++qq) {
        const int q = w * 4 + qq;
        const float s = part[0][q][lane] + part[1][q][lane]
                      + part[2][q][lane] + part[3][q][lane];
        const float x = s * rn;              // NaN (masked q row) -> dropped
        const float t = (x + 1.0f) * (NB * 0.5f);
        int bin = (int)floorf(t);
        bin = bin < 0 ? 0 : (bin > NB - 1 ? NB - 1 : bin);
        if (rowok && x >= -1.0f && x <= 1.0f)
            atomicAdd(&whist[q * NB + bin], 1);
    }
    __syncthreads();

    // flush block histogram to global
    for (int i = tid; i < Q_ * NB; i += 256) {
        const int v = whist[i];
        if (v) atomicAdd(&hist[b * Q_ * NB + i], v);
    }
}

// ---------------- Kernel 3: log1p + FFN + gated sum ----------------
__global__ __launch_bounds__(64) void drmm_final(
    const int* __restrict__ hist, const float* __restrict__ gbuf,
    const int* __restrict__ query,
    const float* __restrict__ W1, const float* __restrict__ b1,
    const float* __restrict__ W2, const float* __restrict__ b2,
    const float* __restrict__ W3, const float* __restrict__ b3,
    float* __restrict__ out)
{
    const int b = blockIdx.x, lane = threadIdx.x;
    float z = 0.f, e = 0.f;
    if (lane < Q_) {
        const int* h = hist + (b * Q_ + lane) * NB;
        float pre1[5];
        #pragma unroll
        for (int u = 0; u < 5; ++u) pre1[u] = b1[u];
        #pragma unroll
        for (int k = 0; k < NB; ++k) {
            const float hv = fast_log1p((float)h[k]);
            #pragma unroll
            for (int u = 0; u < 5; ++u) pre1[u] = fmaf(hv, W1[k * 5 + u], pre1[u]);
        }
        float z2 = b2[0];
        #pragma unroll
        for (int u = 0; u < 5; ++u) z2 = fmaf(fast_tanh(pre1[u]), W2[u], z2);
        const float z3 = fmaf(fast_tanh(z2), W3[0], b3[0]);
        z = fast_tanh(z3);
        const int id = query[b * Q_ + lane];
        const float g = gbuf[b * Q_ + lane];
        e = (id > 0) ? __expf(g) : 0.f;
    }
    float ze = z * e, se = e;
    #pragma unroll
    for (int off = 32; off > 0; off >>= 1) {
        ze += __shfl_xor(ze, off);
        se += __shfl_xor(se, off);
    }
    if (lane == 0) out[b] = ze / (se + 1e-5f);
}

// ---------------- launch ----------------
extern "C" void kernel_launch(void* const* d_in, const int* in_sizes, int n_in,
                              void* d_out, int out_size, void* d_ws, size_t ws_size,
                              hipStream_t stream)
{
    const int*   query = (const int*)d_in[0];
    const int*   doc   = (const int*)d_in[1];
    // d_in[2] = q_idf (unused by reference)
    const float* emb   = (const float*)d_in[3];
    const float* W1    = (const float*)d_in[4];
    const float* b1    = (const float*)d_in[5];
    const float* W2    = (const float*)d_in[6];
    const float* b2    = (const float*)d_in[7];
    const float* W3    = (const float*)d_in[8];
    const float* b3    = (const float*)d_in[9];
    const float* Wg    = (const float*)d_in[10];
    const float* bg    = (const float*)d_in[11];
    float* out = (float*)d_out;

    // workspace layout
    char* ws = (char*)d_ws;
    float* qn   = (float*)ws;                        // 512*300 f32 = 614400 B
    float* gbuf = (float*)(ws + 614400);             // 512 f32    = 2048 B
    int*   hist = (int*)(ws + 614400 + 2048);        // 15360 ints = 61440 B

    drmm_prep<<<B_, 256, 0, stream>>>(query, emb, Wg, bg, qn, gbuf, hist);
    drmm_main<<<B_ * TPB, 256, 0, stream>>>(doc, emb, qn, hist);
    drmm_final<<<B_, 64, 0, stream>>>(hist, gbuf, query,
                                      W1, b1, W2, b2, W3, b3, out);
}

// Round 4
// 50.029 us; speedup vs baseline: 1.4900x; 1.0158x over previous
//
#include <hip/hip_runtime.h>

#define B_ 32
#define Q_ 16
#define D_ 2048
#define E_ 300
#define EF4 75              // float4s per embedding row
#define NB 30
#define TILE 64             // doc rows per block
#define TPB (D_ / TILE)     // tiles per batch = 32

// Hardware-TRANS-pipe transcendentals: single v_exp_f32 / v_log_f32 instead of
// branchy ocml slow paths (R2 post-mortem: drmm_final was 99% stalled on these).
__device__ __forceinline__ float fast_tanh(float x) {
    const float t = __expf(-2.0f * fabsf(x));      // (0,1], never overflows
    const float r = (1.0f - t) / (1.0f + t);
    return copysignf(r, x);
}
__device__ __forceinline__ float fast_log1p(float x) {   // x >= 0 here
    return __logf(1.0f + x);
}

// ---------------- Kernel 1: query prep (qn, gate logits) + hist zero ----------------
__global__ __launch_bounds__(256) void drmm_prep(
    const int* __restrict__ query, const float* __restrict__ emb,
    const float* __restrict__ Wg, const float* __restrict__ bg,
    float* __restrict__ qn, float* __restrict__ gbuf, int* __restrict__ hist)
{
    const int b = blockIdx.x, tid = threadIdx.x;
    const int wid = tid >> 6, lane = tid & 63;

    // zero global histogram (32*16*30 ints) across the 32 blocks
    for (int i = b * 256 + tid; i < B_ * Q_ * NB; i += B_ * 256) hist[i] = 0;

    for (int qq = wid; qq < Q_; qq += 4) {
        const int id = query[b * Q_ + qq];
        const float m = (id > 0) ? 1.f : 0.f;
        const float* row = emb + (long long)((id > 0) ? id : 0) * E_;
        float v[5];
        float ss = 0.f, dg = 0.f;
        #pragma unroll
        for (int k = 0; k < 5; ++k) {
            const int e = lane + 64 * k;
            float x = 0.f, w = 0.f;
            if (e < E_) { x = row[e] * m; w = Wg[e]; }
            v[k] = x;
            ss = fmaf(x, x, ss);
            dg = fmaf(x, w, dg);
        }
        #pragma unroll
        for (int off = 32; off > 0; off >>= 1) {
            ss += __shfl_xor(ss, off);
            dg += __shfl_xor(dg, off);
        }
        // masked row: ss==0 -> rn=inf -> qn = 0*inf = NaN, matching reference 0/0
        const float rn = 1.0f / sqrtf(ss);
        #pragma unroll
        for (int k = 0; k < 5; ++k) {
            const int e = lane + 64 * k;
            if (e < E_) qn[((size_t)(b * Q_ + qq)) * E_ + e] = v[k] * rn;
        }
        if (lane == 0) gbuf[b * Q_ + qq] = fast_tanh(dg + bg[0]);
    }
}

// ---------------- Kernel 2: interaction dots + histogram ----------------
// Block = 64 doc rows (lane = row), 4 waves split E into float4 chunks
// {19,19,19,18}. qn is read DIRECTLY FROM GLOBAL with wave-uniform addresses
// -> compiler emits s_load through the scalar cache; the FMA takes the q
// element as its SGPR operand. No LDS in the inner loop (R3 post-mortem:
// 16 ds_read_b128 per k-step made the LDS pipe the bottleneck, ~24 us/CU).
// Grid is batch-minor so co-resident blocks on a CU share one batch's 19.2 KB
// qn working set in the scalar/L1 caches.
__global__ __launch_bounds__(256, 4) void drmm_main(
    const int* __restrict__ doc, const float* __restrict__ emb,
    const float* __restrict__ qn, int* __restrict__ hist)
{
    __shared__ float part[4][Q_ + 1][TILE];          // 4*17*64*4 = 17408 B
    __shared__ int   whist[Q_ * NB];                 // 1920 B

    const int tid = threadIdx.x;
    const int b = blockIdx.x % B_, tile = blockIdx.x / B_;   // batch-minor
    const int lane = tid & 63;
    const int w = __builtin_amdgcn_readfirstlane(tid >> 6);  // wave-uniform SGPR

    for (int i = tid; i < Q_ * NB; i += 256) whist[i] = 0;
    __syncthreads();

    const int d = tile * TILE + lane;
    const int id = doc[b * D_ + d];
    const bool rowok = (id > 0);
    const float4* row = (const float4*)(emb + (long long)(rowok ? id : 0) * E_);
    const float4* qb4 = (const float4*)(qn + (size_t)b * Q_ * E_);

    const int cbeg = w * 19;                 // chunks: 19,19,19,18 float4s
    const int cnt  = (w == 3) ? 18 : 19;

    float acc[Q_];
    #pragma unroll
    for (int q = 0; q < Q_; ++q) acc[q] = 0.f;
    float ss = 0.f;

    #pragma unroll 4
    for (int k = 0; k < cnt; ++k) {
        const int c = cbeg + k;
        const float4 v = row[c];             // per-lane row, scattered (VMEM)
        ss = fmaf(v.x, v.x, fmaf(v.y, v.y, fmaf(v.z, v.z, fmaf(v.w, v.w, ss))));
        #pragma unroll
        for (int q = 0; q < Q_; ++q) {
            const float4 u = qb4[q * EF4 + c];   // wave-uniform -> s_load (SMEM)
            acc[q] = fmaf(v.x, u.x, fmaf(v.y, u.y, fmaf(v.z, u.z, fmaf(v.w, u.w, acc[q]))));
        }
    }

    // write partial dots + partial sumsq
    #pragma unroll
    for (int q = 0; q < Q_; ++q) part[w][q][lane] = acc[q];
    part[w][Q_][lane] = ss;
    __syncthreads();

    // combine across waves; wave w bins q in [4w, 4w+4)
    const float sst = part[0][Q_][lane] + part[1][Q_][lane]
                    + part[2][Q_][lane] + part[3][Q_][lane];
    const float rn = 1.0f / sqrtf(sst);      // zeros -> inf -> NaN sims -> dropped
    #pragma unroll
    for (int qq = 0; qq < 4; ++qq) {
        const int q = w * 4 + qq;
        const float s = part[0][q][lane] + part[1][q][lane]
                      + part[2][q][lane] + part[3][q][lane];
        const float x = s * rn;              // NaN (masked q row) -> dropped
        const float t = (x + 1.0f) * (NB * 0.5f);
        int bin = (int)floorf(t);
        bin = bin < 0 ? 0 : (bin > NB - 1 ? NB - 1 : bin);
        if (rowok && x >= -1.0f && x <= 1.0f)
            atomicAdd(&whist[q * NB + bin], 1);
    }
    __syncthreads();

    // flush block histogram to global
    for (int i = tid; i < Q_ * NB; i += 256) {
        const int v = whist[i];
        if (v) atomicAdd(&hist[b * Q_ * NB + i], v);
    }
}

// ---------------- Kernel 3: log1p + FFN + gated sum ----------------
__global__ __launch_bounds__(64) void drmm_final(
    const int* __restrict__ hist, const float* __restrict__ gbuf,
    const int* __restrict__ query,
    const float* __restrict__ W1, const float* __restrict__ b1,
    const float* __restrict__ W2, const float* __restrict__ b2,
    const float* __restrict__ W3, const float* __restrict__ b3,
    float* __restrict__ out)
{
    const int b = blockIdx.x, lane = threadIdx.x;
    float z = 0.f, e = 0.f;
    if (lane < Q_) {
        const int* h = hist + (b * Q_ + lane) * NB;
        float pre1[5];
        #pragma unroll
        for (int u = 0; u < 5; ++u) pre1[u] = b1[u];
        #pragma unroll
        for (int k = 0; k < NB; ++k) {
            const float hv = fast_log1p((float)h[k]);
            #pragma unroll
            for (int u = 0; u < 5; ++u) pre1[u] = fmaf(hv, W1[k * 5 + u], pre1[u]);
        }
        float z2 = b2[0];
        #pragma unroll
        for (int u = 0; u < 5; ++u) z2 = fmaf(fast_tanh(pre1[u]), W2[u], z2);
        const float z3 = fmaf(fast_tanh(z2), W3[0], b3[0]);
        z = fast_tanh(z3);
        const int id = query[b * Q_ + lane];
        const float g = gbuf[b * Q_ + lane];
        e = (id > 0) ? __expf(g) : 0.f;
    }
    float ze = z * e, se = e;
    #pragma unroll
    for (int off = 32; off > 0; off >>= 1) {
        ze += __shfl_xor(ze, off);
        se += __shfl_xor(se, off);
    }
    if (lane == 0) out[b] = ze / (se + 1e-5f);
}

// ---------------- launch ----------------
extern "C" void kernel_launch(void* const* d_in, const int* in_sizes, int n_in,
                              void* d_out, int out_size, void* d_ws, size_t ws_size,
                              hipStream_t stream)
{
    const int*   query = (const int*)d_in[0];
    const int*   doc   = (const int*)d_in[1];
    // d_in[2] = q_idf (unused by reference)
    const float* emb   = (const float*)d_in[3];
    const float* W1    = (const float*)d_in[4];
    const float* b1    = (const float*)d_in[5];
    const float* W2    = (const float*)d_in[6];
    const float* b2    = (const float*)d_in[7];
    const float* W3    = (const float*)d_in[8];
    const float* b3    = (const float*)d_in[9];
    const float* Wg    = (const float*)d_in[10];
    const float* bg    = (const float*)d_in[11];
    float* out = (float*)d_out;

    // workspace layout
    char* ws = (char*)d_ws;
    float* qn   = (float*)ws;                        // 512*300 f32 = 614400 B
    float* gbuf = (float*)(ws + 614400);             // 512 f32    = 2048 B
    int*   hist = (int*)(ws + 614400 + 2048);        // 15360 ints = 61440 B

    drmm_prep<<<B_, 256, 0, stream>>>(query, emb, Wg, bg, qn, gbuf, hist);
    drmm_main<<<B_ * TPB, 256, 0, stream>>>(doc, emb, qn, hist);
    drmm_final<<<B_, 64, 0, stream>>>(hist, gbuf, query,
                                      W1, b1, W2, b2, W3, b3, out);
}

// Round 5
// 49.879 us; speedup vs baseline: 1.4945x; 1.0030x over previous
//
#include <hip/hip_runtime.h>

#define B_ 32
#define Q_ 16
#define D_ 2048
#define E_ 300
#define EF4 75              // float4s per embedding row
#define NB 30
#define TILE 64             // doc rows per block
#define TPB (D_ / TILE)     // tiles per batch = 32

// Hardware-TRANS-pipe transcendentals (R2 post-mortem: ocml tanhf/log1pf left
// drmm_final 99% stalled).
__device__ __forceinline__ float fast_tanh(float x) {
    const float t = __expf(-2.0f * fabsf(x));      // (0,1], never overflows
    const float r = (1.0f - t) / (1.0f + t);
    return copysignf(r, x);
}
__device__ __forceinline__ float fast_log1p(float x) {   // x >= 0 here
    return __logf(1.0f + x);
}

// ---------------- Kernel 1: query prep (qn, gate logits) + hist zero ----------------
__global__ __launch_bounds__(256) void drmm_prep(
    const int* __restrict__ query, const float* __restrict__ emb,
    const float* __restrict__ Wg, const float* __restrict__ bg,
    float* __restrict__ qn, float* __restrict__ gbuf, int* __restrict__ hist)
{
    const int b = blockIdx.x, tid = threadIdx.x;
    const int wid = tid >> 6, lane = tid & 63;

    for (int i = b * 256 + tid; i < B_ * Q_ * NB; i += B_ * 256) hist[i] = 0;

    for (int qq = wid; qq < Q_; qq += 4) {
        const int id = query[b * Q_ + qq];
        const float m = (id > 0) ? 1.f : 0.f;
        const float* row = emb + (long long)((id > 0) ? id : 0) * E_;
        float v[5];
        float ss = 0.f, dg = 0.f;
        #pragma unroll
        for (int k = 0; k < 5; ++k) {
            const int e = lane + 64 * k;
            float x = 0.f, w = 0.f;
            if (e < E_) { x = row[e] * m; w = Wg[e]; }
            v[k] = x;
            ss = fmaf(x, x, ss);
            dg = fmaf(x, w, dg);
        }
        #pragma unroll
        for (int off = 32; off > 0; off >>= 1) {
            ss += __shfl_xor(ss, off);
            dg += __shfl_xor(dg, off);
        }
        // masked row: ss==0 -> rn=inf -> qn = 0*inf = NaN, matching reference 0/0
        const float rn = 1.0f / sqrtf(ss);
        #pragma unroll
        for (int k = 0; k < 5; ++k) {
            const int e = lane + 64 * k;
            if (e < E_) qn[((size_t)(b * Q_ + qq)) * E_ + e] = v[k] * rn;
        }
        if (lane == 0) gbuf[b * Q_ + qq] = fast_tanh(dg + bg[0]);
    }
}

// ---------------- Kernel 2: interaction dots + histogram ----------------
// Block = 64 doc rows (lane = row), 4 waves split E {19,19,19,18} float4s.
// qn staged in LDS once per block (one 19.2KB coalesced burst at block start);
// inner-loop qs reads are wave-uniform ds_read_b128 broadcasts (conflict-free).
// R4 post-mortem: per-k-step scalar s_loads of qn spread 19.6MB of K$-missing
// reads across the whole kernel and doubled L2-miss traffic (87MB vs ~45MB
// compulsory). Block mapping groups 4 batches per XCD (xcd = blk&7) so each
// XCD's qn working set is 76.8KB.
__global__ __launch_bounds__(256, 4) void drmm_main(
    const int* __restrict__ doc, const float* __restrict__ emb,
    const float* __restrict__ qn, int* __restrict__ hist)
{
    __shared__ __align__(16) float qs[Q_ * E_];      // 19200 B
    __shared__ float part[4][Q_ + 1][TILE];          // 17408 B
    __shared__ int   whist[Q_ * NB];                 // 1920 B

    const int tid = threadIdx.x;
    // XCD-grouped decode: xcd = blk&7 hosts batches {xcd, 8+xcd, 16+xcd, 24+xcd}
    const int blk = blockIdx.x;
    const int xcd = blk & 7;
    const int j   = blk >> 3;                        // 0..127
    const int b   = ((j & 3) << 3) | xcd;            // 0..31
    const int tile = j >> 2;                         // 0..31
    const int lane = tid & 63, w = tid >> 6;

    // stage qn tile (one coalesced burst) + zero block histogram
    const float4* qb = (const float4*)(qn + (size_t)b * Q_ * E_);
    float4* qs4w = (float4*)qs;
    for (int i = tid; i < Q_ * EF4; i += 256) qs4w[i] = qb[i];
    for (int i = tid; i < Q_ * NB; i += 256) whist[i] = 0;
    __syncthreads();

    const int d = tile * TILE + lane;
    const int id = doc[b * D_ + d];
    const bool rowok = (id > 0);
    const float4* row = (const float4*)(emb + (long long)(rowok ? id : 0) * E_);
    const float4* qs4 = (const float4*)qs;

    const int cbeg = w * 19;                 // chunks: 19,19,19,18 float4s
    const int cnt  = (w == 3) ? 18 : 19;

    float acc[Q_];
    #pragma unroll
    for (int q = 0; q < Q_; ++q) acc[q] = 0.f;
    float ss = 0.f;

    #pragma unroll 4
    for (int k = 0; k < cnt; ++k) {
        const int c = cbeg + k;
        const float4 v = row[c];             // per-lane row, scattered (VMEM)
        ss = fmaf(v.x, v.x, fmaf(v.y, v.y, fmaf(v.z, v.z, fmaf(v.w, v.w, ss))));
        #pragma unroll
        for (int q = 0; q < Q_; ++q) {
            const float4 u = qs4[q * EF4 + c];   // wave-uniform LDS broadcast
            acc[q] = fmaf(v.x, u.x, fmaf(v.y, u.y, fmaf(v.z, u.z, fmaf(v.w, u.w, acc[q]))));
        }
    }

    // write partial dots + partial sumsq
    #pragma unroll
    for (int q = 0; q < Q_; ++q) part[w][q][lane] = acc[q];
    part[w][Q_][lane] = ss;
    __syncthreads();

    // combine across waves; wave w bins q in [4w, 4w+4)
    const float sst = part[0][Q_][lane] + part[1][Q_][lane]
                    + part[2][Q_][lane] + part[3][Q_][lane];
    const float rn = 1.0f / sqrtf(sst);      // zeros -> inf -> NaN sims -> dropped
    #pragma unroll
    for (int qq = 0; qq < 4; ++qq) {
        const int q = w * 4 + qq;
        const float s = part[0][q][lane] + part[1][q][lane]
                      + part[2][q][lane] + part[3][q][lane];
        const float x = s * rn;              // NaN (masked q row) -> dropped
        const float t = (x + 1.0f) * (NB * 0.5f);
        int bin = (int)floorf(t);
        bin = bin < 0 ? 0 : (bin > NB - 1 ? NB - 1 : bin);
        if (rowok && x >= -1.0f && x <= 1.0f)
            atomicAdd(&whist[q * NB + bin], 1);
    }
    __syncthreads();

    // flush block histogram to global
    for (int i = tid; i < Q_ * NB; i += 256) {
        const int v = whist[i];
        if (v) atomicAdd(&hist[b * Q_ * NB + i], v);
    }
}

// ---------------- Kernel 3: log1p + FFN + gated sum ----------------
__global__ __launch_bounds__(64) void drmm_final(
    const int* __restrict__ hist, const float* __restrict__ gbuf,
    const int* __restrict__ query,
    const float* __restrict__ W1, const float* __restrict__ b1,
    const float* __restrict__ W2, const float* __restrict__ b2,
    const float* __restrict__ W3, const float* __restrict__ b3,
    float* __restrict__ out)
{
    const int b = blockIdx.x, lane = threadIdx.x;
    float z = 0.f, e = 0.f;
    if (lane < Q_) {
        const int* h = hist + (b * Q_ + lane) * NB;
        float pre1[5];
        #pragma unroll
        for (int u = 0; u < 5; ++u) pre1[u] = b1[u];
        #pragma unroll
        for (int k = 0; k < NB; ++k) {
            const float hv = fast_log1p((float)h[k]);
            #pragma unroll
            for (int u = 0; u < 5; ++u) pre1[u] = fmaf(hv, W1[k * 5 + u], pre1[u]);
        }
        float z2 = b2[0];
        #pragma unroll
        for (int u = 0; u < 5; ++u) z2 = fmaf(fast_tanh(pre1[u]), W2[u], z2);
        const float z3 = fmaf(fast_tanh(z2), W3[0], b3[0]);
        z = fast_tanh(z3);
        const int id = query[b * Q_ + lane];
        const float g = gbuf[b * Q_ + lane];
        e = (id > 0) ? __expf(g) : 0.f;
    }
    float ze = z * e, se = e;
    #pragma unroll
    for (int off = 32; off > 0; off >>= 1) {
        ze += __shfl_xor(ze, off);
        se += __shfl_xor(se, off);
    }
    if (lane == 0) out[b] = ze / (se + 1e-5f);
}

// ---------------- launch ----------------
extern "C" void kernel_launch(void* const* d_in, const int* in_sizes, int n_in,
                              void* d_out, int out_size, void* d_ws, size_t ws_size,
                              hipStream_t stream)
{
    const int*   query = (const int*)d_in[0];
    const int*   doc   = (const int*)d_in[1];
    // d_in[2] = q_idf (unused by reference)
    const float* emb   = (const float*)d_in[3];
    const float* W1    = (const float*)d_in[4];
    const float* b1    = (const float*)d_in[5];
    const float* W2    = (const float*)d_in[6];
    const float* b2    = (const float*)d_in[7];
    const float* W3    = (const float*)d_in[8];
    const float* b3    = (const float*)d_in[9];
    const float* Wg    = (const float*)d_in[10];
    const float* bg    = (const float*)d_in[11];
    float* out = (float*)d_out;

    // workspace layout
    char* ws = (char*)d_ws;
    float* qn   = (float*)ws;                        // 512*300 f32 = 614400 B
    float* gbuf = (float*)(ws + 614400);             // 512 f32    = 2048 B
    int*   hist = (int*)(ws + 614400 + 2048);        // 15360 ints = 61440 B

    drmm_prep<<<B_, 256, 0, stream>>>(query, emb, Wg, bg, qn, gbuf, hist);
    drmm_main<<<B_ * TPB, 256, 0, stream>>>(doc, emb, qn, hist);
    drmm_final<<<B_, 64, 0, stream>>>(hist, gbuf, query,
                                      W1, b1, W2, b2, W3, b3, out);
}

// Round 6
// 47.790 us; speedup vs baseline: 1.5598x; 1.0437x over previous
//
#include <hip/hip_runtime.h>

#define B_ 32
#define Q_ 16
#define D_ 2048
#define E_ 300
#define EF4 75              // float4s per embedding row
#define NB 30
#define TILE 128            // doc rows per block (2 per lane)
#define TPB (D_ / TILE)     // tiles per batch = 16

// Hardware-TRANS-pipe transcendentals (R2 post-mortem: ocml tanhf/log1pf left
// drmm_final 99% stalled).
__device__ __forceinline__ float fast_tanh(float x) {
    const float t = __expf(-2.0f * fabsf(x));      // (0,1], never overflows
    const float r = (1.0f - t) / (1.0f + t);
    return copysignf(r, x);
}
__device__ __forceinline__ float fast_log1p(float x) {   // x >= 0 here
    return __logf(1.0f + x);
}

// ---------------- Kernel 1: query prep (qn, gate logits) + hist zero ----------------
__global__ __launch_bounds__(256) void drmm_prep(
    const int* __restrict__ query, const float* __restrict__ emb,
    const float* __restrict__ Wg, const float* __restrict__ bg,
    float* __restrict__ qn, float* __restrict__ gbuf, int* __restrict__ hist)
{
    const int b = blockIdx.x, tid = threadIdx.x;
    const int wid = tid >> 6, lane = tid & 63;

    for (int i = b * 256 + tid; i < B_ * Q_ * NB; i += B_ * 256) hist[i] = 0;

    for (int qq = wid; qq < Q_; qq += 4) {
        const int id = query[b * Q_ + qq];
        const float m = (id > 0) ? 1.f : 0.f;
        const float* row = emb + (long long)((id > 0) ? id : 0) * E_;
        float v[5];
        float ss = 0.f, dg = 0.f;
        #pragma unroll
        for (int k = 0; k < 5; ++k) {
            const int e = lane + 64 * k;
            float x = 0.f, w = 0.f;
            if (e < E_) { x = row[e] * m; w = Wg[e]; }
            v[k] = x;
            ss = fmaf(x, x, ss);
            dg = fmaf(x, w, dg);
        }
        #pragma unroll
        for (int off = 32; off > 0; off >>= 1) {
            ss += __shfl_xor(ss, off);
            dg += __shfl_xor(dg, off);
        }
        // masked row: ss==0 -> rn=inf -> qn = 0*inf = NaN, matching reference 0/0
        const float rn = 1.0f / sqrtf(ss);
        #pragma unroll
        for (int k = 0; k < 5; ++k) {
            const int e = lane + 64 * k;
            if (e < E_) qn[((size_t)(b * Q_ + qq)) * E_ + e] = v[k] * rn;
        }
        if (lane == 0) gbuf[b * Q_ + qq] = fast_tanh(dg + bg[0]);
    }
}

// ---------------- Kernel 2: interaction dots + histogram ----------------
// Block = 128 doc rows, 2 per lane (rA=lane, rB=lane+64); 4 waves split E into
// float4 chunks {19,19,19,18}. Each lane PREFETCHES its full row chunks into
// registers (va/vb) before the FMA loop -> ~38 outstanding 16B loads/lane for
// memory-level parallelism (R5 post-mortem: dependent-load chain capped the
// gather at 1.9 TB/s). Each wave-uniform ds_read_b128 of q feeds BOTH rows'
// FMAs -> LDS traffic halved vs 1 row/lane. The {19,19,19,18} tail is a
// common 18-step body + one wave-uniform extra step for waves 0-2.
__global__ __launch_bounds__(256, 2) void drmm_main(
    const int* __restrict__ doc, const float* __restrict__ emb,
    const float* __restrict__ qn, int* __restrict__ hist)
{
    __shared__ __align__(16) float qs[Q_ * E_];      // 19200 B
    __shared__ float part[4][Q_ + 1][TILE];          // 34816 B
    __shared__ int   whist[Q_ * NB];                 // 1920 B

    const int tid = threadIdx.x;
    // XCD-grouped decode: xcd = blk&7 hosts batches {xcd, 8+xcd, 16+xcd, 24+xcd}
    const int blk = blockIdx.x;                      // 0..511
    const int xcd = blk & 7;
    const int j   = blk >> 3;                        // 0..63
    const int b   = ((j & 3) << 3) | xcd;            // 0..31
    const int tile = j >> 2;                         // 0..15
    const int lane = tid & 63, w = tid >> 6;

    // stage qn tile (one coalesced burst) + zero block histogram
    const float4* qb = (const float4*)(qn + (size_t)b * Q_ * E_);
    float4* qs4w = (float4*)qs;
    for (int i = tid; i < Q_ * EF4; i += 256) qs4w[i] = qb[i];
    for (int i = tid; i < Q_ * NB; i += 256) whist[i] = 0;
    __syncthreads();

    const int dbase = b * D_ + tile * TILE + lane;
    const int idA = doc[dbase];
    const int idB = doc[dbase + 64];
    const bool okA = (idA > 0), okB = (idB > 0);
    const int cbeg = w * 19;                 // chunks: 19,19,19,18 float4s
    const bool extra = (w < 3);              // waves 0-2 do a 19th element
    const float4* rA = ((const float4*)(emb + (long long)(okA ? idA : 0) * E_)) + cbeg;
    const float4* rB = ((const float4*)(emb + (long long)(okB ? idB : 0) * E_)) + cbeg;
    const float4* qs4 = (const float4*)qs;

    // -------- prefetch both row chunks into registers (MLP) --------
    float4 va[19], vb[19];
    #pragma unroll
    for (int k = 0; k < 18; ++k) { va[k] = rA[k]; vb[k] = rB[k]; }
    if (extra) { va[18] = rA[18]; vb[18] = rB[18]; }

    float accA[Q_], accB[Q_];
    #pragma unroll
    for (int q = 0; q < Q_; ++q) { accA[q] = 0.f; accB[q] = 0.f; }
    float ssA = 0.f, ssB = 0.f;

    #pragma unroll
    for (int k = 0; k < 18; ++k) {
        const float4 a = va[k], c = vb[k];
        ssA = fmaf(a.x, a.x, fmaf(a.y, a.y, fmaf(a.z, a.z, fmaf(a.w, a.w, ssA))));
        ssB = fmaf(c.x, c.x, fmaf(c.y, c.y, fmaf(c.z, c.z, fmaf(c.w, c.w, ssB))));
        #pragma unroll
        for (int q = 0; q < Q_; ++q) {
            const float4 u = qs4[q * EF4 + cbeg + k];   // broadcast, feeds 2 rows
            accA[q] = fmaf(a.x, u.x, fmaf(a.y, u.y, fmaf(a.z, u.z, fmaf(a.w, u.w, accA[q]))));
            accB[q] = fmaf(c.x, u.x, fmaf(c.y, u.y, fmaf(c.z, u.z, fmaf(c.w, u.w, accB[q]))));
        }
    }
    if (extra) {
        const float4 a = va[18], c = vb[18];
        ssA = fmaf(a.x, a.x, fmaf(a.y, a.y, fmaf(a.z, a.z, fmaf(a.w, a.w, ssA))));
        ssB = fmaf(c.x, c.x, fmaf(c.y, c.y, fmaf(c.z, c.z, fmaf(c.w, c.w, ssB))));
        #pragma unroll
        for (int q = 0; q < Q_; ++q) {
            const float4 u = qs4[q * EF4 + cbeg + 18];
            accA[q] = fmaf(a.x, u.x, fmaf(a.y, u.y, fmaf(a.z, u.z, fmaf(a.w, u.w, accA[q]))));
            accB[q] = fmaf(c.x, u.x, fmaf(c.y, u.y, fmaf(c.z, u.z, fmaf(c.w, u.w, accB[q]))));
        }
    }

    // write partial dots + partial sumsq for both rows
    #pragma unroll
    for (int q = 0; q < Q_; ++q) {
        part[w][q][lane]      = accA[q];
        part[w][q][lane + 64] = accB[q];
    }
    part[w][Q_][lane]      = ssA;
    part[w][Q_][lane + 64] = ssB;
    __syncthreads();

    // combine across waves; thread handles 8 q's for one row
    {
        const int r  = tid & 127;
        const int qh = (tid >> 7) * 8;
        const float sst = part[0][Q_][r] + part[1][Q_][r]
                        + part[2][Q_][r] + part[3][Q_][r];
        const float rn = 1.0f / sqrtf(sst);  // zeros -> inf -> NaN sims -> dropped
        const bool rok = (r < 64) ? ((doc[b * D_ + tile * TILE + r]) > 0)
                                  : ((doc[b * D_ + tile * TILE + r]) > 0);
        #pragma unroll
        for (int qq = 0; qq < 8; ++qq) {
            const int q = qh + qq;
            const float s = part[0][q][r] + part[1][q][r]
                          + part[2][q][r] + part[3][q][r];
            const float x = s * rn;          // NaN (masked q row) -> dropped
            const float t = (x + 1.0f) * (NB * 0.5f);
            int bin = (int)floorf(t);
            bin = bin < 0 ? 0 : (bin > NB - 1 ? NB - 1 : bin);
            if (rok && x >= -1.0f && x <= 1.0f)
                atomicAdd(&whist[q * NB + bin], 1);
        }
    }
    __syncthreads();

    // flush block histogram to global
    for (int i = tid; i < Q_ * NB; i += 256) {
        const int v = whist[i];
        if (v) atomicAdd(&hist[b * Q_ * NB + i], v);
    }
}

// ---------------- Kernel 3: log1p + FFN + gated sum ----------------
__global__ __launch_bounds__(64) void drmm_final(
    const int* __restrict__ hist, const float* __restrict__ gbuf,
    const int* __restrict__ query,
    const float* __restrict__ W1, const float* __restrict__ b1,
    const float* __restrict__ W2, const float* __restrict__ b2,
    const float* __restrict__ W3, const float* __restrict__ b3,
    float* __restrict__ out)
{
    const int b = blockIdx.x, lane = threadIdx.x;
    float z = 0.f, e = 0.f;
    if (lane < Q_) {
        const int* h = hist + (b * Q_ + lane) * NB;
        float pre1[5];
        #pragma unroll
        for (int u = 0; u < 5; ++u) pre1[u] = b1[u];
        #pragma unroll
        for (int k = 0; k < NB; ++k) {
            const float hv = fast_log1p((float)h[k]);
            #pragma unroll
            for (int u = 0; u < 5; ++u) pre1[u] = fmaf(hv, W1[k * 5 + u], pre1[u]);
        }
        float z2 = b2[0];
        #pragma unroll
        for (int u = 0; u < 5; ++u) z2 = fmaf(fast_tanh(pre1[u]), W2[u], z2);
        const float z3 = fmaf(fast_tanh(z2), W3[0], b3[0]);
        z = fast_tanh(z3);
        const int id = query[b * Q_ + lane];
        const float g = gbuf[b * Q_ + lane];
        e = (id > 0) ? __expf(g) : 0.f;
    }
    float ze = z * e, se = e;
    #pragma unroll
    for (int off = 32; off > 0; off >>= 1) {
        ze += __shfl_xor(ze, off);
        se += __shfl_xor(se, off);
    }
    if (lane == 0) out[b] = ze / (se + 1e-5f);
}

// ---------------- launch ----------------
extern "C" void kernel_launch(void* const* d_in, const int* in_sizes, int n_in,
                              void* d_out, int out_size, void* d_ws, size_t ws_size,
                              hipStream_t stream)
{
    const int*   query = (const int*)d_in[0];
    const int*   doc   = (const int*)d_in[1];
    // d_in[2] = q_idf (unused by reference)
    const float* emb   = (const float*)d_in[3];
    const float* W1    = (const float*)d_in[4];
    const float* b1    = (const float*)d_in[5];
    const float* W2    = (const float*)d_in[6];
    const float* b2    = (const float*)d_in[7];
    const float* W3    = (const float*)d_in[8];
    const float* b3    = (const float*)d_in[9];
    const float* Wg    = (const float*)d_in[10];
    const float* bg    = (const float*)d_in[11];
    float* out = (float*)d_out;

    // workspace layout
    char* ws = (char*)d_ws;
    float* qn   = (float*)ws;                        // 512*300 f32 = 614400 B
    float* gbuf = (float*)(ws + 614400);             // 512 f32    = 2048 B
    int*   hist = (int*)(ws + 614400 + 2048);        // 15360 ints = 61440 B

    drmm_prep<<<B_, 256, 0, stream>>>(query, emb, Wg, bg, qn, gbuf, hist);
    drmm_main<<<B_ * TPB, 256, 0, stream>>>(doc, emb, qn, hist);
    drmm_final<<<B_, 64, 0, stream>>>(hist, gbuf, query,
                                      W1, b1, W2, b2, W3, b3, out);
}